// Round 4
// baseline (233.454 us; speedup 1.0000x reference)
//
#include <hip/hip_runtime.h>
#include <hip/hip_bf16.h>
#include <cstdint>
#include <cstddef>

// Problem constants (L=256, C=20, LC=5120, BATCH=1024)
#define LCN 5120
#define BN  1024
#define CN  20

typedef __attribute__((ext_vector_type(4))) float  floatx4;
typedef __attribute__((ext_vector_type(8))) short  shortx8;
typedef __attribute__((ext_vector_type(4))) unsigned short ushortx4;

static __device__ __forceinline__ unsigned short f2bf(float f) {
    __hip_bfloat16 h = __float2bfloat16(f);
    return *reinterpret_cast<unsigned short*>(&h);
}

static __device__ __forceinline__ void gload_lds16(const void* g, void* l) {
    __builtin_amdgcn_global_load_lds(
        (const __attribute__((address_space(1))) void*)g,
        (__attribute__((address_space(3))) void*)l,
        16, 0, 0);
}

// ---------------------------------------------------------------------------
// Pass 1a: streaming masked convert, NATIVE layout (no transpose!).
//   Tn[a*5120 + k] = bf16(theta[a*5120 + k]) if k >= 20*(a/20+1) else 0
// (mask l(k) > l(a) is a per-row SUFFIX since k-index order == l order.)
// Fully coalesced read (4 KB/wavefront-quarter) and write (2 KB). Blocks whose
// 1024-col span lies entirely below the first chunk k_quad reads for this
// row's n-tile are pruned (never read -> may stay poisoned).
// ---------------------------------------------------------------------------
__global__ __launch_bounds__(256) void k_conv(const float* __restrict__ th,
                                              unsigned short* __restrict__ Tn) {
    const int a  = blockIdx.y;                       // row (output index)
    const int t  = a >> 7;                           // n-tile = a/128
    const int c0 = (CN * ((128 * t) / CN + 1)) / 512;  // first chunk read for tile
    const int bx = blockIdx.x;
    if (2 * (bx + 1) <= c0) return;                  // block covers chunks 2bx,2bx+1
    const int kmin = CN * (a / CN + 1);              // row suffix start
    const int col  = bx * 1024 + threadIdx.x * 4;
    const floatx4 v = *reinterpret_cast<const floatx4*>(th + (size_t)a * LCN + col);
    ushortx4 o;
#pragma unroll
    for (int e = 0; e < 4; ++e)
        o[e] = (col + e >= kmin) ? f2bf(v[e]) : (unsigned short)0;
    *reinterpret_cast<ushortx4*>(Tn + (size_t)a * LCN + col) = o;
}

// ---------------------------------------------------------------------------
// Pass 1b: fused  out[b] = theta_0 + sum_i theta_lc[i]*x[b,i]  (fp32, exact)
//          and    Xb[b,i] = bf16(x[b,i])
// ---------------------------------------------------------------------------
__global__ __launch_bounds__(256) void k_init(const float* __restrict__ x,
                                              const float* __restrict__ th0,
                                              const float* __restrict__ thlc,
                                              float* __restrict__ out,
                                              unsigned short* __restrict__ Xb) {
    const int b = blockIdx.x;
    const int tid = threadIdx.x;
    const floatx4* xr = reinterpret_cast<const floatx4*>(x + (size_t)b * LCN);
    const floatx4* tr = reinterpret_cast<const floatx4*>(thlc);
    ushortx4* xw = reinterpret_cast<ushortx4*>(Xb + (size_t)b * LCN);
    float s = 0.0f;
    for (int k = tid; k < LCN / 4; k += 256) {
        const floatx4 a = xr[k], t2 = tr[k];
        s += a[0] * t2[0] + a[1] * t2[1] + a[2] * t2[2] + a[3] * t2[3];
        ushortx4 o;
#pragma unroll
        for (int e = 0; e < 4; ++e) o[e] = f2bf(a[e]);
        xw[k] = o;
    }
#pragma unroll
    for (int off = 32; off > 0; off >>= 1) s += __shfl_down(s, off, 64);
    __shared__ float ws4[4];
    if ((tid & 63) == 0) ws4[tid >> 6] = s;
    __syncthreads();
    if (tid == 0) out[b] = th0[0] + ws4[0] + ws4[1] + ws4[2] + ws4[3];
}

// ---------------------------------------------------------------------------
// Pass 2: masked-GEMM + fused dot-reduce (m97 structure, 128x128 tile, BK=32).
//   Z[b,a] = sum_k Xb[b,k] * Tn[a,k]   (Tn zero where masked)
//   out[b] += sum_a Z[b,a] * x[b,a]
// XCD-pinned 1-D grid decode (id%8 round-robin). Suffix chunk table:
//   c0(t) = (20*(128t/20+1))/512, chunks(t) = 10 - c0(t), total 220.
// LDS segment swizzle (R3, conflicts=0) kept.
// ---------------------------------------------------------------------------
__global__ __launch_bounds__(256) void k_quad(
    const unsigned short* __restrict__ Xb,   // [1024][5120] bf16
    const unsigned short* __restrict__ Tn,   // [5120][5120] bf16, native rows
    float*                __restrict__ out,  // [1024]
    const int tot)                           // total chunk count (220)
{
    const int bid  = blockIdx.x;
    const int xcd  = bid & 7;
    const int slot = bid >> 3;
    const int m    = slot & 7;
    const int g    = slot >> 3;
    int q = g * 8 + xcd;
    if (q >= tot) return;

    __shared__ unsigned short As[128 * 32];
    __shared__ unsigned short Bs[128 * 32];
    __shared__ float partial[128];

    const int tid  = threadIdx.x;
    const int lane = tid & 63;
    const int w    = tid >> 6;        // wave 0..3
    const int wm   = w & 1;           // M half
    const int wn   = w >> 1;          // N half
    const int lrow = lane & 15;
    const int kq   = lane >> 4;       // 0..3

    // map chunk ordinal q -> (n-tile, absolute chunk c)
    int n = 0, c = 0;
    for (int t = 0; t < 40; ++t) {
        const int c0t = (CN * ((128 * t) / CN + 1)) / 512;
        const int chn = 10 - c0t;
        if (q < chn) { n = t; c = c0t + q; break; }
        q -= chn;
    }
    const int b0 = m * 128;
    const int n0 = n * 128;
    const int k0 = c * 512;

    if (tid < 128) partial[tid] = 0.0f;

    floatx4 acc[4][4];
#pragma unroll
    for (int mt = 0; mt < 4; ++mt)
#pragma unroll
        for (int nt = 0; nt < 4; ++nt) acc[mt][nt] = (floatx4)0.0f;

    // swizzled fragment offsets (ushort units): seg = (kq + (row>>1)) & 3
    int aoff[4], boff[4];
#pragma unroll
    for (int mt = 0; mt < 4; ++mt) {
        const int row = wm * 64 + mt * 16 + lrow;
        aoff[mt] = row * 32 + (((kq + (row >> 1)) & 3) << 3);
    }
#pragma unroll
    for (int nt = 0; nt < 4; ++nt) {
        const int row = wn * 64 + nt * 16 + lrow;
        boff[nt] = row * 32 + (((kq + (row >> 1)) & 3) << 3);
    }

    for (int kk = 0; kk < 16; ++kk) {
        const int kc = k0 + kk * 32;
        // stage A/B: 512 x 16B segs per tile; LDS slot (row,seg) holds global
        // segment ((seg - (row>>1)) & 3) of that row.
#pragma unroll
        for (int t = 0; t < 2; ++t) {
            const int s    = t * 256 + tid;
            const int row  = s >> 2;
            const int gseg = ((s & 3) - (row >> 1)) & 3;
            char* la = (char*)As + (size_t)(t * 256 + w * 64) * 16;  // wave-uniform
            char* lb = (char*)Bs + (size_t)(t * 256 + w * 64) * 16;
            gload_lds16(Xb + (size_t)(b0 + row) * LCN + kc + gseg * 8, la);
            gload_lds16(Tn + (size_t)(n0 + row) * LCN + kc + gseg * 8, lb);
        }
        __syncthreads();

        shortx8 af[4], bfr[4];
#pragma unroll
        for (int mt = 0; mt < 4; ++mt)
            af[mt] = *reinterpret_cast<const shortx8*>(As + aoff[mt]);
#pragma unroll
        for (int nt = 0; nt < 4; ++nt)
            bfr[nt] = *reinterpret_cast<const shortx8*>(Bs + boff[nt]);
#pragma unroll
        for (int mt = 0; mt < 4; ++mt)
#pragma unroll
            for (int nt = 0; nt < 4; ++nt)
                acc[mt][nt] = __builtin_amdgcn_mfma_f32_16x16x32_bf16(af[mt], bfr[nt], acc[mt][nt], 0, 0, 0);
        __syncthreads();
    }

    // Epilogue: C/D layout col = lane&15 (a), row = (lane>>4)*4 + reg (batch)
#pragma unroll
    for (int mt = 0; mt < 4; ++mt) {
#pragma unroll
        for (int r = 0; r < 4; ++r) {
            const int b = b0 + wm * 64 + mt * 16 + kq * 4 + r;
            float s = 0.0f;
#pragma unroll
            for (int nt = 0; nt < 4; ++nt) {
                const int a = n0 + wn * 64 + nt * 16 + lrow;
                const __hip_bfloat16 hv = *reinterpret_cast<const __hip_bfloat16*>(&Xb[(size_t)b * LCN + a]);
                s += acc[mt][nt][r] * __bfloat162float(hv);
            }
            s += __shfl_xor(s, 1, 64);
            s += __shfl_xor(s, 2, 64);
            s += __shfl_xor(s, 4, 64);
            s += __shfl_xor(s, 8, 64);
            if (lrow == 0) atomicAdd(&partial[b - b0], s);
        }
    }
    __syncthreads();
    if (tid < 128) atomicAdd(&out[b0 + tid], partial[tid]);
}

// ---------------------------------------------------------------------------
extern "C" void kernel_launch(void* const* d_in, const int* in_sizes, int n_in,
                              void* d_out, int out_size, void* d_ws, size_t ws_size,
                              hipStream_t stream) {
    const float* x      = (const float*)d_in[0];  // [1024, 5120]
    const float* th0    = (const float*)d_in[1];  // [1]
    const float* thlc   = (const float*)d_in[2];  // [5120]
    const float* thlclc = (const float*)d_in[3];  // [5120, 5120]
    float* out = (float*)d_out;                   // [1024]

    // ws layout: Tn (bf16 5120x5120 = 52.4 MB) | Xb (bf16 1024x5120 = 10.5 MB)
    unsigned short* Tn = (unsigned short*)d_ws;
    unsigned short* Xb = (unsigned short*)((char*)d_ws + (size_t)LCN * LCN * 2);

    k_conv<<<dim3(LCN / 1024, LCN), 256, 0, stream>>>(thlclc, Tn);
    k_init<<<dim3(BN), 256, 0, stream>>>(x, th0, thlc, out, Xb);

    int tot = 0;
    for (int t = 0; t < 40; ++t) {
        const int c0t = (CN * ((128 * t) / CN + 1)) / 512;
        tot += 10 - c0t;
    }
    const int groups = (tot + 7) / 8;             // 28
    k_quad<<<dim3(groups * 64), 256, 0, stream>>>(Xb, Tn, out, tot);
}

// Round 5
// 232.123 us; speedup vs baseline: 1.0057x; 1.0057x over previous
//
#include <hip/hip_runtime.h>
#include <hip/hip_bf16.h>
#include <cstdint>
#include <cstddef>

// Problem constants (L=256, C=20, LC=5120, BATCH=1024)
#define LCN 5120
#define BN  1024
#define CN  20

typedef __attribute__((ext_vector_type(4))) float  floatx4;
typedef __attribute__((ext_vector_type(8))) short  shortx8;
typedef __attribute__((ext_vector_type(4))) unsigned short ushortx4;

static __device__ __forceinline__ unsigned short f2bf(float f) {
    __hip_bfloat16 h = __float2bfloat16(f);
    return *reinterpret_cast<unsigned short*>(&h);
}

static __device__ __forceinline__ void gload_lds16(const void* g, void* l) {
    __builtin_amdgcn_global_load_lds(
        (const __attribute__((address_space(1))) void*)g,
        (__attribute__((address_space(3))) void*)l,
        16, 0, 0);
}

// ---------------------------------------------------------------------------
// Pass 1a: streaming masked convert, NATIVE layout (unchanged from R4).
//   Tn[a*5120 + k] = bf16(theta[a*5120 + k]) if k >= 20*(a/20+1) else 0
// ---------------------------------------------------------------------------
__global__ __launch_bounds__(256) void k_conv(const float* __restrict__ th,
                                              unsigned short* __restrict__ Tn) {
    const int a  = blockIdx.y;
    const int t  = a >> 7;
    const int c0 = (CN * ((128 * t) / CN + 1)) / 512;
    const int bx = blockIdx.x;
    if (2 * (bx + 1) <= c0) return;
    const int kmin = CN * (a / CN + 1);
    const int col  = bx * 1024 + threadIdx.x * 4;
    const floatx4 v = *reinterpret_cast<const floatx4*>(th + (size_t)a * LCN + col);
    ushortx4 o;
#pragma unroll
    for (int e = 0; e < 4; ++e)
        o[e] = (col + e >= kmin) ? f2bf(v[e]) : (unsigned short)0;
    *reinterpret_cast<ushortx4*>(Tn + (size_t)a * LCN + col) = o;
}

// ---------------------------------------------------------------------------
// Pass 1b: fused lin-term + x convert (unchanged from R4).
// ---------------------------------------------------------------------------
__global__ __launch_bounds__(256) void k_init(const float* __restrict__ x,
                                              const float* __restrict__ th0,
                                              const float* __restrict__ thlc,
                                              float* __restrict__ out,
                                              unsigned short* __restrict__ Xb) {
    const int b = blockIdx.x;
    const int tid = threadIdx.x;
    const floatx4* xr = reinterpret_cast<const floatx4*>(x + (size_t)b * LCN);
    const floatx4* tr = reinterpret_cast<const floatx4*>(thlc);
    ushortx4* xw = reinterpret_cast<ushortx4*>(Xb + (size_t)b * LCN);
    float s = 0.0f;
    for (int k = tid; k < LCN / 4; k += 256) {
        const floatx4 a = xr[k], t2 = tr[k];
        s += a[0] * t2[0] + a[1] * t2[1] + a[2] * t2[2] + a[3] * t2[3];
        ushortx4 o;
#pragma unroll
        for (int e = 0; e < 4; ++e) o[e] = f2bf(a[e]);
        xw[k] = o;
    }
#pragma unroll
    for (int off = 32; off > 0; off >>= 1) s += __shfl_down(s, off, 64);
    __shared__ float ws4[4];
    if ((tid & 63) == 0) ws4[tid >> 6] = s;
    __syncthreads();
    if (tid == 0) out[b] = th0[0] + ws4[0] + ws4[1] + ws4[2] + ws4[3];
}

// ---------------------------------------------------------------------------
// Pass 2: masked-GEMM + fused dot-reduce.
// R5 change: PING-PONG LDS double buffer, ONE barrier per K-iteration.
//   prologue: stage chunk 0 into buf0
//   iter kk:  barrier (drains loads into buf[kk&1]; also fences last reads of
//             buf[kk&1^1]) -> issue loads(kk+1) into buf[kk&1^1] -> ds_read +
//             MFMA from buf[kk&1].
// Load latency for kk+1 overlaps compute of kk; barrier count 32 -> 17.
// XCD-pinned decode + segment swizzle (conflicts=0) unchanged.
// ---------------------------------------------------------------------------
__global__ __launch_bounds__(256) void k_quad(
    const unsigned short* __restrict__ Xb,   // [1024][5120] bf16
    const unsigned short* __restrict__ Tn,   // [5120][5120] bf16, native rows
    float*                __restrict__ out,  // [1024]
    const int tot)                           // total chunk count (220)
{
    const int bid  = blockIdx.x;
    const int xcd  = bid & 7;
    const int slot = bid >> 3;
    const int m    = slot & 7;
    const int g    = slot >> 3;
    int q = g * 8 + xcd;
    if (q >= tot) return;

    __shared__ unsigned short As[2][128 * 32];
    __shared__ unsigned short Bs[2][128 * 32];
    __shared__ float partial[128];

    const int tid  = threadIdx.x;
    const int lane = tid & 63;
    const int w    = tid >> 6;        // wave 0..3
    const int wm   = w & 1;
    const int wn   = w >> 1;
    const int lrow = lane & 15;
    const int kq   = lane >> 4;

    // map chunk ordinal q -> (n-tile, absolute chunk c)
    int n = 0, c = 0;
    for (int t = 0; t < 40; ++t) {
        const int c0t = (CN * ((128 * t) / CN + 1)) / 512;
        const int chn = 10 - c0t;
        if (q < chn) { n = t; c = c0t + q; break; }
        q -= chn;
    }
    const int b0 = m * 128;
    const int n0 = n * 128;
    const int k0 = c * 512;

    if (tid < 128) partial[tid] = 0.0f;

    floatx4 acc[4][4];
#pragma unroll
    for (int mt = 0; mt < 4; ++mt)
#pragma unroll
        for (int nt = 0; nt < 4; ++nt) acc[mt][nt] = (floatx4)0.0f;

    // staging addresses (per-thread constants): 2 segs per tile per thread
    // LDS slot (row,seg) holds global segment ((seg - (row>>1)) & 3)
    int grow[2], goff[2], loff[2];
#pragma unroll
    for (int t = 0; t < 2; ++t) {
        const int s    = t * 256 + tid;
        const int row  = s >> 2;
        const int gseg = ((s & 3) - (row >> 1)) & 3;
        grow[t] = row;
        goff[t] = gseg * 8;
        loff[t] = (t * 256 + w * 64) * 16;   // wave-uniform byte offset
    }
    // swizzled fragment offsets (ushort units)
    int aoff[4], boff[4];
#pragma unroll
    for (int mt = 0; mt < 4; ++mt) {
        const int row = wm * 64 + mt * 16 + lrow;
        aoff[mt] = row * 32 + (((kq + (row >> 1)) & 3) << 3);
    }
#pragma unroll
    for (int nt = 0; nt < 4; ++nt) {
        const int row = wn * 64 + nt * 16 + lrow;
        boff[nt] = row * 32 + (((kq + (row >> 1)) & 3) << 3);
    }

    // prologue: stage chunk 0 into buffer 0
#pragma unroll
    for (int t = 0; t < 2; ++t) {
        gload_lds16(Xb + (size_t)(b0 + grow[t]) * LCN + k0 + goff[t], (char*)As[0] + loff[t]);
        gload_lds16(Tn + (size_t)(n0 + grow[t]) * LCN + k0 + goff[t], (char*)Bs[0] + loff[t]);
    }

    for (int kk = 0; kk < 16; ++kk) {
        const int p = kk & 1;
        __syncthreads();   // drains loads into buf[p]; fences last reads of buf[p^1]
        if (kk < 15) {
            const int kc = k0 + (kk + 1) * 32;
#pragma unroll
            for (int t = 0; t < 2; ++t) {
                gload_lds16(Xb + (size_t)(b0 + grow[t]) * LCN + kc + goff[t], (char*)As[p ^ 1] + loff[t]);
                gload_lds16(Tn + (size_t)(n0 + grow[t]) * LCN + kc + goff[t], (char*)Bs[p ^ 1] + loff[t]);
            }
        }
        shortx8 af[4], bfr[4];
#pragma unroll
        for (int mt = 0; mt < 4; ++mt)
            af[mt] = *reinterpret_cast<const shortx8*>(As[p] + aoff[mt]);
#pragma unroll
        for (int nt = 0; nt < 4; ++nt)
            bfr[nt] = *reinterpret_cast<const shortx8*>(Bs[p] + boff[nt]);
#pragma unroll
        for (int mt = 0; mt < 4; ++mt)
#pragma unroll
            for (int nt = 0; nt < 4; ++nt)
                acc[mt][nt] = __builtin_amdgcn_mfma_f32_16x16x32_bf16(af[mt], bfr[nt], acc[mt][nt], 0, 0, 0);
    }

    // Epilogue (unchanged): C/D layout col = lane&15 (a), row = quad*4 + reg (b)
#pragma unroll
    for (int mt = 0; mt < 4; ++mt) {
#pragma unroll
        for (int r = 0; r < 4; ++r) {
            const int b = b0 + wm * 64 + mt * 16 + kq * 4 + r;
            float s = 0.0f;
#pragma unroll
            for (int nt = 0; nt < 4; ++nt) {
                const int a = n0 + wn * 64 + nt * 16 + lrow;
                const __hip_bfloat16 hv = *reinterpret_cast<const __hip_bfloat16*>(&Xb[(size_t)b * LCN + a]);
                s += acc[mt][nt][r] * __bfloat162float(hv);
            }
            s += __shfl_xor(s, 1, 64);
            s += __shfl_xor(s, 2, 64);
            s += __shfl_xor(s, 4, 64);
            s += __shfl_xor(s, 8, 64);
            if (lrow == 0) atomicAdd(&partial[b - b0], s);
        }
    }
    __syncthreads();
    if (tid < 128) atomicAdd(&out[b0 + tid], partial[tid]);
}

// ---------------------------------------------------------------------------
extern "C" void kernel_launch(void* const* d_in, const int* in_sizes, int n_in,
                              void* d_out, int out_size, void* d_ws, size_t ws_size,
                              hipStream_t stream) {
    const float* x      = (const float*)d_in[0];
    const float* th0    = (const float*)d_in[1];
    const float* thlc   = (const float*)d_in[2];
    const float* thlclc = (const float*)d_in[3];
    float* out = (float*)d_out;

    unsigned short* Tn = (unsigned short*)d_ws;
    unsigned short* Xb = (unsigned short*)((char*)d_ws + (size_t)LCN * LCN * 2);

    k_conv<<<dim3(LCN / 1024, LCN), 256, 0, stream>>>(thlclc, Tn);
    k_init<<<dim3(BN), 256, 0, stream>>>(x, th0, thlc, out, Xb);

    int tot = 0;
    for (int t = 0; t < 40; ++t) {
        const int c0t = (CN * ((128 * t) / CN + 1)) / 512;
        tot += 10 - c0t;
    }
    const int groups = (tot + 7) / 8;             // 28
    k_quad<<<dim3(groups * 64), 256, 0, stream>>>(Xb, Tn, out, tot);
}